// Round 18
// baseline (257.074 us; speedup 1.0000x reference)
//
#include <hip/hip_runtime.h>
#include <hip/hip_cooperative_groups.h>
#include <stdint.h>

namespace cg = cooperative_groups;

#define N_NODES 50000
#define N_EDGES 800000
#define IN_CH 128
#define HIDDEN 16
#define OUT_CH 64
#define ROWCAP 48                        // per-node CSR slots (96B region)
#define NBB 782                          // buckets (dst>>6), 64 nodes each
#define NPAD (NBB * 64)                  // 50048 padded node slots
#define OVFCAP 64                        // per-bucket overflow slots

#define PEB 1024                         // edges per partition block
#define PB ((N_EDGES + PEB - 1) / PEB)   // 782 partition work items
#define LB ((N_NODES + 31) / 32)         // 1563 linear1 work items
#define OB (N_NODES / 4)                 // 12500 out work items (4 nodes each)

#define SMEM_FLOATS (IN_CH * 36 + 32 * (IN_CH + 1))   // 8736 floats = 34944 B

// ===========================================================================
// Phase bodies (shared between the cooperative mega-kernel and the 3-kernel
// fallback). All R17-proven logic; smem is a 34944B block-shared buffer.
// ===========================================================================

// ---- partition: counting-sort 1024 edges into 782 bins, owner-computes ----
__device__ __forceinline__ void part_body(
    int blk, float* __restrict__ smem, const int* __restrict__ ei,
    int* __restrict__ bucket, uint16_t* __restrict__ base16)
{
    int* stg   = (int*)smem;                 // [1024]
    int* hist  = stg + 1024;                 // [784]
    int* cur   = hist + 784;                 // [784]
    int* wsum  = cur + 784;                  // [4]
    int* lflag = wsum + 4;
    const int t = threadIdx.x;
    const int e0 = blk * PEB;
    const int lane = t & 63;
    const int wid  = t >> 6;

    if (t < 64) {
        const int v = ei[2 * t + 1];
        const unsigned long long b = __ballot(v != 0);
        if (t == 0) *lflag = (b == 0ull);
    }
    for (int i = t; i < 784; i += 256) hist[i] = 0;
    __syncthreads();
    const int is64 = *lflag;

    int srcs[4], dsts[4];
    #pragma unroll
    for (int k = 0; k < 4; ++k) {
        const int e = e0 + t + k * 256;
        int src = 0, dst = -1;
        if (e < N_EDGES) {
            if (is64) {
                src = ((const int2*)ei)[e].x;
                dst = ((const int2*)ei)[N_EDGES + e].x;
            } else {
                src = ei[e];
                dst = ei[N_EDGES + e];
            }
            atomicAdd(&hist[dst >> 6], 1);               // LDS atomic
        }
        srcs[k] = src; dsts[k] = dst;
    }
    __syncthreads();

    // hierarchical exclusive scan: 4 bins/thread + wave shfl + 4-entry scan
    int tot = 0;
    #pragma unroll
    for (int j = 0; j < 4; ++j) {
        const int idx = 4 * t + j;
        if (idx < 784) tot += hist[idx];
    }
    int inc = tot;
    #pragma unroll
    for (int off = 1; off < 64; off <<= 1) {
        const int u = __shfl_up(inc, off);
        if (lane >= off) inc += u;
    }
    if (lane == 63) wsum[wid] = inc;
    __syncthreads();
    if (t == 0) {
        int run = 0;
        #pragma unroll
        for (int w = 0; w < 4; ++w) { const int v = wsum[w]; wsum[w] = run; run += v; }
    }
    __syncthreads();
    int run = inc - tot + wsum[wid];
    #pragma unroll
    for (int j = 0; j < 4; ++j) {
        const int idx = 4 * t + j;
        if (idx < 784) {
            cur[idx] = run;
            base16[blk * 784 + idx] = (uint16_t)run;
            run += hist[idx];
        }
    }
    __syncthreads();

    #pragma unroll
    for (int k = 0; k < 4; ++k) {
        if (dsts[k] >= 0) {
            const int bin = dsts[k] >> 6;
            const int pos = atomicAdd(&cur[bin], 1);     // LDS atomic
            stg[pos] = ((dsts[k] & 63) << 16) | srcs[k];
        }
    }
    __syncthreads();

    ((int4*)(bucket + (size_t)blk * PEB))[t] = ((const int4*)stg)[t];
}

// ---- linear1: y1 = x@W1l, z1 = x@W1r for 32 nodes ----
__device__ __forceinline__ void lin1_body(
    int item, float* __restrict__ smem, const float* __restrict__ x,
    const float* __restrict__ W1l, const float* __restrict__ W1r,
    float* __restrict__ y1, float* __restrict__ z1)
{
    float (*sW)[36] = (float(*)[36])smem;                  // [128][36]
    float (*sx)[IN_CH + 1] = (float(*)[IN_CH + 1])(smem + IN_CH * 36);
    const int t = threadIdx.x;

    for (int i = t; i < IN_CH * HIDDEN; i += 256) {
        int k = i / HIDDEN, c = i % HIDDEN;
        sW[k][c]      = W1l[i];
        sW[k][c + 16] = W1r[i];
    }

    const int node0 = item * 32;
    for (int i = t; i < 32 * (IN_CH / 4); i += 256) {
        int r    = i / (IN_CH / 4);
        int col4 = i % (IN_CH / 4);
        int node = node0 + r;
        float4 v = make_float4(0.f, 0.f, 0.f, 0.f);
        if (node < N_NODES)
            v = ((const float4*)x)[node * (IN_CH / 4) + col4];
        sx[r][col4 * 4 + 0] = v.x;
        sx[r][col4 * 4 + 1] = v.y;
        sx[r][col4 * 4 + 2] = v.z;
        sx[r][col4 * 4 + 3] = v.w;
    }
    __syncthreads();

    const int r    = t & 31;
    const int og   = t >> 5;
    const int node = node0 + r;

    float4 acc = make_float4(0.f, 0.f, 0.f, 0.f);
    #pragma unroll 4
    for (int k = 0; k < IN_CH; ++k) {
        const float xv = sx[r][k];
        const float4 w4 = *(const float4*)&sW[k][og * 4];  // ds_read_b128
        acc.x += xv * w4.x;
        acc.y += xv * w4.y;
        acc.z += xv * w4.z;
        acc.w += xv * w4.w;
    }

    if (node < N_NODES) {
        const int oc = og * 4;
        float vals[4] = {acc.x, acc.y, acc.z, acc.w};
        #pragma unroll
        for (int j = 0; j < 4; ++j) {
            int o = oc + j;
            if (o < HIDDEN) y1[node * HIDDEN + o]            = vals[j];
            else            z1[node * HIDDEN + (o - HIDDEN)] = vals[j];
        }
    }
}

// ---- bin + gather_h for one 64-node bucket ----
__device__ __forceinline__ void binh_body(
    int b, float* __restrict__ smem,
    const int* __restrict__ bucket, const uint16_t* __restrict__ base16,
    uint16_t* __restrict__ row, int* __restrict__ cnt,
    int* __restrict__ govf, int* __restrict__ ovfcnt,
    const float* __restrict__ y1, float* __restrict__ z1h,
    const float* __restrict__ b1l)
{
    uint16_t (*stg)[ROWCAP] = (uint16_t(*)[ROWCAP])smem;   // [64][48] 6KB
    int* cntl   = (int*)(smem + 1536);                     // [64]
    int* ovfc   = cntl + 64;                               // [1]
    int* govf_l = ovfc + 1;                                // [OVFCAP]
    const int t = threadIdx.x;

    if (t < 64) cntl[t] = 0;
    if (t == 64) *ovfc = 0;
    __syncthreads();

    // phase A: bin
    for (int pb = t; pb < PB; pb += 256) {
        const int lo = base16[pb * 784 + b];
        const int hi = base16[pb * 784 + b + 1];
        const int* bp = bucket + (size_t)pb * PEB;
        for (int i = lo; i < hi; ++i) {
            const int w   = bp[i];
            const int nl  = (w >> 16) & 63;
            const int src = w & 0xFFFF;
            const int pos = atomicAdd(&cntl[nl], 1);       // LDS atomic
            if (pos < ROWCAP) {
                stg[nl][pos] = (uint16_t)src;
            } else {
                const int o = atomicAdd(ovfc, 1);          // LDS atomic
                if (o < OVFCAP) { govf[b * OVFCAP + o] = w; govf_l[o] = w; }
            }
        }
    }
    __syncthreads();

    // stream out row/cnt/ovfcnt for the out phase
    {
        const uint4* s4 = (const uint4*)&stg[0][0];
        uint4* d4 = (uint4*)(row + (size_t)b * 64 * ROWCAP);
        for (int i = t; i < 384; i += 256) d4[i] = s4[i];
        if (t < 64) cnt[b * 64 + t] = cntl[t];
        if (t == 64) ovfcnt[b] = min(*ovfc, OVFCAP);
    }

    // phase B: gather y1 for own 64 nodes (indices stay in LDS)
    const int nl = t >> 2;
    const int q  = t & 3;
    const int n  = b * 64 + nl;
    const int dgr   = cntl[nl];
    const int slots = dgr < ROWCAP ? dgr : ROWCAP;

    float4 s = make_float4(0.f, 0.f, 0.f, 0.f);
    int i = 0;
    for (; i + 4 <= slots; i += 4) {
        const int j0 = stg[nl][i + 0];
        const int j1 = stg[nl][i + 1];
        const int j2 = stg[nl][i + 2];
        const int j3 = stg[nl][i + 3];
        const float4 v0 = ((const float4*)(y1 + j0 * HIDDEN))[q];
        const float4 v1 = ((const float4*)(y1 + j1 * HIDDEN))[q];
        const float4 v2 = ((const float4*)(y1 + j2 * HIDDEN))[q];
        const float4 v3 = ((const float4*)(y1 + j3 * HIDDEN))[q];
        s.x += (v0.x + v1.x) + (v2.x + v3.x);
        s.y += (v0.y + v1.y) + (v2.y + v3.y);
        s.z += (v0.z + v1.z) + (v2.z + v3.z);
        s.w += (v0.w + v1.w) + (v2.w + v3.w);
    }
    for (; i < slots; ++i) {
        const int j = stg[nl][i];
        const float4 v = ((const float4*)(y1 + j * HIDDEN))[q];
        s.x += v.x; s.y += v.y; s.z += v.z; s.w += v.w;
    }

    if (dgr > ROWCAP) {
        const int on = min(*ovfc, OVFCAP);
        for (int o = 0; o < on; ++o) {
            const int w = govf_l[o];
            if (((w >> 16) & 63) == nl) {
                const float4 v = ((const float4*)(y1 + (w & 0xFFFF) * HIDDEN))[q];
                s.x += v.x; s.y += v.y; s.z += v.z; s.w += v.w;
            }
        }
    }

    if (n < N_NODES) {
        const float inv = 1.0f / fmaxf((float)dgr, 1.0f);
        const float4 b4 = ((const float4*)b1l)[q];
        float4* zp = (float4*)(z1h + (size_t)n * HIDDEN) + q;
        const float4 z4 = *zp;
        float4 hv;
        hv.x = fmaxf(s.x * inv + b4.x + z4.x, 0.f);
        hv.y = fmaxf(s.y * inv + b4.y + z4.y, 0.f);
        hv.z = fmaxf(s.z * inv + b4.z + z4.z, 0.f);
        hv.w = fmaxf(s.w * inv + b4.w + z4.w, 0.f);
        *zp = hv;                                          // z1 -> h in place
    }
    __syncthreads();   // protect LDS reuse across work-loop iterations
}

// ---- out phase: float4-quartered gather core ----
__device__ __forceinline__ float4 gather_rows_f4(
    const float* __restrict__ feat, const uint16_t* __restrict__ rp,
    int slots, int ri, int q)
{
    float4 s = make_float4(0.f, 0.f, 0.f, 0.f);
    int i = 0;
    while (i + 16 < slots) {
        const int j0 = rp[i + ri];
        const int idx1 = i + 16 + ri;
        const bool p1 = idx1 < slots;
        const int j1 = p1 ? rp[idx1] : 0;
        const float4 v0 = ((const float4*)(feat + j0 * HIDDEN))[q];
        float4 v1 = make_float4(0.f, 0.f, 0.f, 0.f);
        if (p1) v1 = ((const float4*)(feat + j1 * HIDDEN))[q];
        s.x += v0.x + v1.x; s.y += v0.y + v1.y;
        s.z += v0.z + v1.z; s.w += v0.w + v1.w;
        i += 32;
    }
    if (i + ri < slots) {
        const int j = rp[i + ri];
        const float4 v = ((const float4*)(feat + j * HIDDEN))[q];
        s.x += v.x; s.y += v.y; s.z += v.z; s.w += v.w;
    }
    #pragma unroll
    for (int off = 4; off <= 32; off <<= 1) {
        s.x += __shfl_xor(s.x, off);
        s.y += __shfl_xor(s.y, off);
        s.z += __shfl_xor(s.z, off);
        s.w += __shfl_xor(s.w, off);
    }
    return s;
}

__device__ __forceinline__ void out_stageW(
    float* __restrict__ smem,
    const float* __restrict__ W2l, const float* __restrict__ W2r)
{
    // sW2[k][s][c] = smem[(k*2+s)*64+c], 2048 floats
    const int t = threadIdx.x;
    for (int i = t; i < HIDDEN * OUT_CH; i += 256) {
        const int k = i / OUT_CH, c = i % OUT_CH;
        smem[(k * 2 + 0) * 64 + c] = W2l[i];
        smem[(k * 2 + 1) * 64 + c] = W2r[i];
    }
}

__device__ __forceinline__ void out_body(
    int item, float* __restrict__ smem,
    const int* __restrict__ cnt, const uint16_t* __restrict__ row,
    const int* __restrict__ govf, const int* __restrict__ ovfcnt,
    const float* __restrict__ h, const float* __restrict__ b2l,
    float* __restrict__ out)
{
    float* sW2 = smem;                    // [2048]
    float* sm  = smem + 2048;             // [4][16]
    float* sh  = smem + 2112;             // [4][16]
    const int t = threadIdx.x;
    const int lane = t & 63;
    const int wid  = t >> 6;              // 0..3
    const int n = item * 4 + wid;
    const int q  = lane & 3;
    const int ri = lane >> 2;

    const int dgr   = cnt[n];
    const int slots = dgr < ROWCAP ? dgr : ROWCAP;
    const uint16_t* rp = row + (size_t)n * ROWCAP;

    float4 s = gather_rows_f4(h, rp, slots, ri, q);

    if (dgr > ROWCAP) {
        const int b = n >> 6;
        const int on = ovfcnt[b];
        for (int o = 0; o < on; ++o) {
            const int w = govf[b * OVFCAP + o];
            if (((w >> 16) & 63) == (n & 63)) {
                const float4 v = ((const float4*)(h + (w & 0xFFFF) * HIDDEN))[q];
                s.x += v.x; s.y += v.y; s.z += v.z; s.w += v.w;
            }
        }
    }

    if (lane < 4) {
        const float inv = 1.0f / fmaxf((float)dgr, 1.0f);
        float4 m4;
        m4.x = s.x * inv; m4.y = s.y * inv; m4.z = s.z * inv; m4.w = s.w * inv;
        ((float4*)(sm + wid * 16))[q] = m4;
        ((float4*)(sh + wid * 16))[q] = ((const float4*)(h + (size_t)n * HIDDEN))[q];
    }
    // sm/sh written+read within the SAME wave -> in-order, no barrier needed

    float acc = b2l[lane];
    #pragma unroll
    for (int k = 0; k < HIDDEN; ++k)
        acc += sm[wid * 16 + k] * sW2[(k * 2) * 64 + lane]
             + sh[wid * 16 + k] * sW2[(k * 2 + 1) * 64 + lane];

    float mx = acc;
    #pragma unroll
    for (int off = 32; off > 0; off >>= 1)
        mx = fmaxf(mx, __shfl_xor(mx, off));
    float ex = expf(acc - mx);
    float sum = ex;
    #pragma unroll
    for (int off = 32; off > 0; off >>= 1)
        sum += __shfl_xor(sum, off);

    out[(size_t)n * OUT_CH + lane] = acc - mx - logf(sum);
}

// ===========================================================================
// Cooperative mega-kernel: part||linear1 -> grid.sync -> bin+gather_h ->
// grid.sync -> out (weights staged once per persistent block).
// ===========================================================================
__global__ __launch_bounds__(256) void k_mega(
    const int* __restrict__ ei, int* __restrict__ bucket,
    uint16_t* __restrict__ base16,
    const float* __restrict__ x,
    const float* __restrict__ W1l, const float* __restrict__ W1r,
    float* __restrict__ y1, float* __restrict__ z1h,
    const float* __restrict__ b1l,
    uint16_t* __restrict__ row, int* __restrict__ cnt,
    int* __restrict__ govf, int* __restrict__ ovfcnt,
    const float* __restrict__ W2l, const float* __restrict__ b2l,
    const float* __restrict__ W2r,
    float* __restrict__ out)
{
    __shared__ __align__(16) float smem[SMEM_FLOATS];
    cg::grid_group grid = cg::this_grid();
    const int nb = gridDim.x;

    // phase 1: partition || linear1
    for (int it = blockIdx.x; it < PB + LB; it += nb) {
        if (it < PB) part_body(it, smem, ei, bucket, base16);
        else         lin1_body(it - PB, smem, x, W1l, W1r, y1, z1h);
        __syncthreads();
    }
    grid.sync();

    // phase 2: bin + gather_h per bucket
    for (int it = blockIdx.x; it < NBB; it += nb)
        binh_body(it, smem, bucket, base16, row, cnt, govf, ovfcnt,
                  y1, z1h, b1l);
    grid.sync();

    // phase 3: out (weights staged once)
    out_stageW(smem, W2l, W2r);
    __syncthreads();
    for (int it = blockIdx.x; it < OB; it += nb)
        out_body(it, smem, cnt, row, govf, ovfcnt, z1h, b2l, out);
}

// ===========================================================================
// Fallback 3-kernel path (R17-equivalent) in case cooperative launch fails.
// ===========================================================================
__global__ __launch_bounds__(256) void k_front(
    const int* __restrict__ ei, int* __restrict__ bucket,
    uint16_t* __restrict__ base16,
    const float* __restrict__ x,
    const float* __restrict__ W1l, const float* __restrict__ W1r,
    float* __restrict__ y1, float* __restrict__ z1)
{
    __shared__ __align__(16) float smem[SMEM_FLOATS];
    if (blockIdx.x < PB) part_body(blockIdx.x, smem, ei, bucket, base16);
    else                 lin1_body(blockIdx.x - PB, smem, x, W1l, W1r, y1, z1);
}

__global__ __launch_bounds__(256) void k_bin_h(
    const int* __restrict__ bucket, const uint16_t* __restrict__ base16,
    uint16_t* __restrict__ row, int* __restrict__ cnt,
    int* __restrict__ govf, int* __restrict__ ovfcnt,
    const float* __restrict__ y1, float* __restrict__ z1h,
    const float* __restrict__ b1l)
{
    __shared__ __align__(16) float smem[SMEM_FLOATS];
    binh_body(blockIdx.x, smem, bucket, base16, row, cnt, govf, ovfcnt,
              y1, z1h, b1l);
}

__global__ __launch_bounds__(256) void k_out(
    const int* __restrict__ cnt, const uint16_t* __restrict__ row,
    const int* __restrict__ govf, const int* __restrict__ ovfcnt,
    const float* __restrict__ h,
    const float* __restrict__ W2l, const float* __restrict__ b2l,
    const float* __restrict__ W2r,
    float* __restrict__ out)
{
    __shared__ __align__(16) float smem[SMEM_FLOATS];
    out_stageW(smem, W2l, W2r);
    __syncthreads();
    out_body(blockIdx.x, smem, cnt, row, govf, ovfcnt, h, b2l, out);
}

// ---------------------------------------------------------------------------
extern "C" void kernel_launch(void* const* d_in, const int* in_sizes, int n_in,
                              void* d_out, int out_size, void* d_ws, size_t ws_size,
                              hipStream_t stream)
{
    const float* x   = (const float*)d_in[0];
    const float* W1l = (const float*)d_in[1];
    const float* b1l = (const float*)d_in[2];
    const float* W1r = (const float*)d_in[3];
    const float* W2l = (const float*)d_in[4];
    const float* b2l = (const float*)d_in[5];
    const float* W2r = (const float*)d_in[6];
    const int*   ei  = (const int*)d_in[7];
    float* out = (float*)d_out;

    const size_t NH = (size_t)N_NODES * HIDDEN;           // 800000
    int*   bucket = (int*)d_ws;                           // [PB*PEB]    3.2 MB
    float* bufA   = (float*)(bucket + (size_t)PB * PEB);  // y1          3.2 MB
    float* bufB   = bufA + NH;                            // z1 -> h     3.2 MB
    int*   cnt    = (int*)(bufB + NH);                    // [NPAD]      0.2 MB
    int*   govf   = cnt + NPAD;                           // [NBB*64]    0.2 MB
    int*   ovfcnt = govf + NBB * OVFCAP;                  // [NBB] (+2 pad)
    uint16_t* base16 = (uint16_t*)(ovfcnt + NBB + 2);     // [PB*784]    1.23 MB
    uint16_t* row    = base16 + (size_t)PB * 784;         // [NPAD*48]   4.8 MB

    // ---- try cooperative mega-kernel (deterministic decision) ----
    int maxB = 0;
    hipError_t qe = hipOccupancyMaxActiveBlocksPerMultiprocessor(&maxB, k_mega, 256, 0);
    int grid = (qe == hipSuccess && maxB > 0) ? maxB * 256 : 0;   // 256 CUs
    if (grid > 2048) grid = 2048;

    hipError_t err = hipErrorUnknown;
    if (grid > 0) {
        void* args[] = {
            (void*)&ei, (void*)&bucket, (void*)&base16,
            (void*)&x, (void*)&W1l, (void*)&W1r,
            (void*)&bufA, (void*)&bufB, (void*)&b1l,
            (void*)&row, (void*)&cnt, (void*)&govf, (void*)&ovfcnt,
            (void*)&W2l, (void*)&b2l, (void*)&W2r, (void*)&out
        };
        err = hipLaunchCooperativeKernel(k_mega, dim3(grid), dim3(256),
                                         args, 0, stream);
    }

    if (err != hipSuccess) {
        (void)hipGetLastError();          // clear sticky error
        // fallback: proven 3-kernel pipeline
        k_front<<<PB + LB, 256, 0, stream>>>(ei, bucket, base16,
                                             x, W1l, W1r, bufA, bufB);
        k_bin_h<<<NBB, 256, 0, stream>>>(bucket, base16, row, cnt, govf,
                                         ovfcnt, bufA, bufB, b1l);
        k_out<<<OB, 256, 0, stream>>>(cnt, row, govf, ovfcnt, bufB,
                                      W2l, b2l, W2r, out);
    }
}

// Round 19
// 76.615 us; speedup vs baseline: 3.3554x; 3.3554x over previous
//
#include <hip/hip_runtime.h>
#include <stdint.h>

#define N_NODES 50000
#define N_EDGES 800000
#define IN_CH 128
#define HIDDEN 16
#define OUT_CH 64
#define ROWCAP 48                        // per-node CSR slots (96B region)
#define NBB 782                          // buckets (dst>>6), 64 nodes each
#define NPAD (NBB * 64)                  // 50048 padded node slots
#define OVFCAP 64                        // per-bucket overflow slots

#define PEB 4096                         // edges per partition block
#define PB ((N_EDGES + PEB - 1) / PEB)   // 196 partition blocks (256 thr x 16)
#define LB ((N_NODES + 31) / 32)         // 1563 linear1-role blocks

// ---------------------------------------------------------------------------
// K1: blocks [0,PB) -> owner-computes partition (256 thr, counting sort of
//     4096 edges into 782 bins; zero global atomics; coalesced stream-out).
//     blocks [PB,PB+LB) -> linear1: y1 = x@W1l, z1 = x@W1r (LDS-tiled).
// PEB=4096 (vs 1024 in R17): bucket b's data now sits in 196 regions with
// runs of ~5.2 edges -> K2's scattered-line fetch drops ~4x (R18 profile
// showed 62MB FETCH from the 1.3-edge runs at PEB=1024).
// ---------------------------------------------------------------------------
__global__ __launch_bounds__(256) void k_front(
    const int* __restrict__ ei,
    int* __restrict__ bucket,            // [PB * PEB]
    uint16_t* __restrict__ base16,       // [PB * 784]
    const float* __restrict__ x,
    const float* __restrict__ W1l, const float* __restrict__ W1r,
    float* __restrict__ y1, float* __restrict__ z1)
{
    __shared__ __align__(16) float smem[IN_CH * 36 + 32 * (IN_CH + 1)]; // 34944B
    const int t = threadIdx.x;

    if (blockIdx.x < PB) {
        // ---- partition role (aliases smem) ----
        int* stg   = (int*)smem;                   // [4096] 16 KB
        int* hist  = stg + PEB;                    // [784]
        int* cur   = hist + 784;                   // [784]
        int* wsum  = cur + 784;                    // [4]
        int* lflag = wsum + 4;
        const int blk = blockIdx.x;
        const int e0 = blk * PEB;
        const int lane = t & 63;
        const int wid  = t >> 6;

        if (t < 64) {
            const int v = ei[2 * t + 1];
            const unsigned long long b = __ballot(v != 0);
            if (t == 0) *lflag = (b == 0ull);
        }
        for (int i = t; i < 784; i += 256) hist[i] = 0;
        __syncthreads();
        const int is64 = *lflag;

        int srcs[16], dsts[16];
        #pragma unroll
        for (int k = 0; k < 16; ++k) {
            const int e = e0 + t + k * 256;
            int src = 0, dst = -1;
            if (e < N_EDGES) {
                if (is64) {
                    src = ((const int2*)ei)[e].x;          // 8B coalesced
                    dst = ((const int2*)ei)[N_EDGES + e].x;
                } else {
                    src = ei[e];
                    dst = ei[N_EDGES + e];
                }
                atomicAdd(&hist[dst >> 6], 1);             // LDS atomic
            }
            srcs[k] = src; dsts[k] = dst;
        }
        __syncthreads();

        // hierarchical exclusive scan: 4 bins/thread + wave shfl + 4-entry scan
        int tot = 0;
        #pragma unroll
        for (int j = 0; j < 4; ++j) {
            const int idx = 4 * t + j;
            if (idx < 784) tot += hist[idx];
        }
        int inc = tot;
        #pragma unroll
        for (int off = 1; off < 64; off <<= 1) {
            const int u = __shfl_up(inc, off);
            if (lane >= off) inc += u;
        }
        if (lane == 63) wsum[wid] = inc;
        __syncthreads();
        if (t == 0) {
            int run = 0;
            #pragma unroll
            for (int w = 0; w < 4; ++w) { const int v = wsum[w]; wsum[w] = run; run += v; }
        }
        __syncthreads();
        int run = inc - tot + wsum[wid];       // exclusive prefix of my chunk
        #pragma unroll
        for (int j = 0; j < 4; ++j) {
            const int idx = 4 * t + j;
            if (idx < 784) {
                cur[idx] = run;
                base16[blk * 784 + idx] = (uint16_t)run;   // bins 782/783 = total
                run += hist[idx];
            }
        }
        __syncthreads();

        #pragma unroll
        for (int k = 0; k < 16; ++k) {
            if (dsts[k] >= 0) {
                const int bin = dsts[k] >> 6;
                const int pos = atomicAdd(&cur[bin], 1);   // LDS atomic
                stg[pos] = ((dsts[k] & 63) << 16) | srcs[k];
            }
        }
        __syncthreads();

        // coalesced stream-out: 4096 ints as 1024 x int4
        int4* dst4 = (int4*)(bucket + (size_t)blk * PEB);
        const int4* src4 = (const int4*)stg;
        for (int i = t; i < PEB / 4; i += 256) dst4[i] = src4[i];
        return;
    }

    // ---- linear1 role ----
    float (*sW)[36] = (float(*)[36])smem;                  // [128][36]
    float (*sx)[IN_CH + 1] = (float(*)[IN_CH + 1])(smem + IN_CH * 36);

    for (int i = t; i < IN_CH * HIDDEN; i += 256) {
        int k = i / HIDDEN, c = i % HIDDEN;
        sW[k][c]      = W1l[i];
        sW[k][c + 16] = W1r[i];
    }

    const int node0 = (blockIdx.x - PB) * 32;
    for (int i = t; i < 32 * (IN_CH / 4); i += 256) {
        int r    = i / (IN_CH / 4);
        int col4 = i % (IN_CH / 4);
        int node = node0 + r;
        float4 v = make_float4(0.f, 0.f, 0.f, 0.f);
        if (node < N_NODES)
            v = ((const float4*)x)[node * (IN_CH / 4) + col4];
        sx[r][col4 * 4 + 0] = v.x;
        sx[r][col4 * 4 + 1] = v.y;
        sx[r][col4 * 4 + 2] = v.z;
        sx[r][col4 * 4 + 3] = v.w;
    }
    __syncthreads();

    const int r    = t & 31;
    const int og   = t >> 5;
    const int node = node0 + r;

    float4 acc = make_float4(0.f, 0.f, 0.f, 0.f);
    #pragma unroll 4
    for (int k = 0; k < IN_CH; ++k) {
        const float xv = sx[r][k];
        const float4 w4 = *(const float4*)&sW[k][og * 4];  // ds_read_b128
        acc.x += xv * w4.x;
        acc.y += xv * w4.y;
        acc.z += xv * w4.z;
        acc.w += xv * w4.w;
    }

    if (node < N_NODES) {
        const int oc = og * 4;
        float vals[4] = {acc.x, acc.y, acc.z, acc.w};
        #pragma unroll
        for (int j = 0; j < 4; ++j) {
            int o = oc + j;
            if (o < HIDDEN) y1[node * HIDDEN + o]            = vals[j];
            else            z1[node * HIDDEN + (o - HIDDEN)] = vals[j];
        }
    }
}

// ---------------------------------------------------------------------------
// K2: one block per bucket (256 thr).
//   Phase A (bin): gather this bucket's runs from all 196 part regions into
//   64-node LDS staging via LDS atomics; stream out row/cnt/ovf for K3.
//   Phase B (gather_h): 4 thr/node gather y1 rows using LDS-resident indices,
//   4-deep ILP float4 loads; h = relu(mean + b1 + z1) in place over z1.
// ---------------------------------------------------------------------------
__global__ __launch_bounds__(256) void k_bin_h(
    const int* __restrict__ bucket, const uint16_t* __restrict__ base16,
    uint16_t* __restrict__ row, int* __restrict__ cnt,
    int* __restrict__ govf, int* __restrict__ ovfcnt,
    const float* __restrict__ y1, float* __restrict__ z1h,
    const float* __restrict__ b1l)
{
    __shared__ __align__(16) uint16_t stg[64][ROWCAP];    // 6 KB
    __shared__ int cntl[64];
    __shared__ int ovfc;
    __shared__ int govf_l[OVFCAP];
    const int t = threadIdx.x;
    const int b = blockIdx.x;

    if (t < 64) cntl[t] = 0;
    if (t == 64) ovfc = 0;
    __syncthreads();

    // ---- phase A: bin ----
    for (int pb = t; pb < PB; pb += 256) {
        const int lo = base16[pb * 784 + b];
        const int hi = base16[pb * 784 + b + 1];
        const int* bp = bucket + (size_t)pb * PEB;
        for (int i = lo; i < hi; ++i) {
            const int w   = bp[i];
            const int nl  = (w >> 16) & 63;
            const int src = w & 0xFFFF;
            const int pos = atomicAdd(&cntl[nl], 1);       // LDS atomic
            if (pos < ROWCAP) {
                stg[nl][pos] = (uint16_t)src;
            } else {
                const int o = atomicAdd(&ovfc, 1);         // LDS atomic
                if (o < OVFCAP) { govf[b * OVFCAP + o] = w; govf_l[o] = w; }
            }
        }
    }
    __syncthreads();

    // stream out row/cnt/ovfcnt for K3
    {
        const uint4* s4 = (const uint4*)stg;
        uint4* d4 = (uint4*)(row + (size_t)b * 64 * ROWCAP);
        for (int i = t; i < 384; i += 256) d4[i] = s4[i];
        if (t < 64) cnt[b * 64 + t] = cntl[t];
        if (t == 64) ovfcnt[b] = min(ovfc, OVFCAP);
    }

    // ---- phase B: gather y1 for own 64 nodes (indices stay in LDS) ----
    const int nl = t >> 2;                 // 0..63
    const int q  = t & 3;                  // feature quarter
    const int n  = b * 64 + nl;
    const int dgr   = cntl[nl];
    const int slots = dgr < ROWCAP ? dgr : ROWCAP;

    float4 s = make_float4(0.f, 0.f, 0.f, 0.f);
    int i = 0;
    for (; i + 4 <= slots; i += 4) {       // 4-deep ILP
        const int j0 = stg[nl][i + 0];
        const int j1 = stg[nl][i + 1];
        const int j2 = stg[nl][i + 2];
        const int j3 = stg[nl][i + 3];
        const float4 v0 = ((const float4*)(y1 + j0 * HIDDEN))[q];
        const float4 v1 = ((const float4*)(y1 + j1 * HIDDEN))[q];
        const float4 v2 = ((const float4*)(y1 + j2 * HIDDEN))[q];
        const float4 v3 = ((const float4*)(y1 + j3 * HIDDEN))[q];
        s.x += (v0.x + v1.x) + (v2.x + v3.x);
        s.y += (v0.y + v1.y) + (v2.y + v3.y);
        s.z += (v0.z + v1.z) + (v2.z + v3.z);
        s.w += (v0.w + v1.w) + (v2.w + v3.w);
    }
    for (; i < slots; ++i) {
        const int j = stg[nl][i];
        const float4 v = ((const float4*)(y1 + j * HIDDEN))[q];
        s.x += v.x; s.y += v.y; s.z += v.z; s.w += v.w;
    }

    if (dgr > ROWCAP) {                    // rare overflow, LDS-resident list
        const int on = min(ovfc, OVFCAP);
        for (int o = 0; o < on; ++o) {
            const int w = govf_l[o];
            if (((w >> 16) & 63) == nl) {
                const float4 v = ((const float4*)(y1 + (w & 0xFFFF) * HIDDEN))[q];
                s.x += v.x; s.y += v.y; s.z += v.z; s.w += v.w;
            }
        }
    }

    if (n < N_NODES) {
        const float inv = 1.0f / fmaxf((float)dgr, 1.0f);
        const float4 b4 = ((const float4*)b1l)[q];
        float4* zp = (float4*)(z1h + (size_t)n * HIDDEN) + q;
        const float4 z4 = *zp;
        float4 hv;
        hv.x = fmaxf(s.x * inv + b4.x + z4.x, 0.f);
        hv.y = fmaxf(s.y * inv + b4.y + z4.y, 0.f);
        hv.z = fmaxf(s.z * inv + b4.z + z4.z, 0.f);
        hv.w = fmaxf(s.w * inv + b4.w + z4.w, 0.f);
        *zp = hv;                          // in-place z1 -> h
    }
}

// ---------------------------------------------------------------------------
// K3: fused gather layer 2 + output (float4-quartered core, R17-identical).
// ---------------------------------------------------------------------------
__device__ __forceinline__ float4 gather_rows_f4(
    const float* __restrict__ feat, const uint16_t* __restrict__ rp,
    int slots, int ri, int q)
{
    float4 s = make_float4(0.f, 0.f, 0.f, 0.f);
    int i = 0;
    while (i + 16 < slots) {
        const int j0 = rp[i + ri];
        const int idx1 = i + 16 + ri;
        const bool p1 = idx1 < slots;
        const int j1 = p1 ? rp[idx1] : 0;
        const float4 v0 = ((const float4*)(feat + j0 * HIDDEN))[q];
        float4 v1 = make_float4(0.f, 0.f, 0.f, 0.f);
        if (p1) v1 = ((const float4*)(feat + j1 * HIDDEN))[q];
        s.x += v0.x + v1.x; s.y += v0.y + v1.y;
        s.z += v0.z + v1.z; s.w += v0.w + v1.w;
        i += 32;
    }
    if (i + ri < slots) {
        const int j = rp[i + ri];
        const float4 v = ((const float4*)(feat + j * HIDDEN))[q];
        s.x += v.x; s.y += v.y; s.z += v.z; s.w += v.w;
    }
    #pragma unroll
    for (int off = 4; off <= 32; off <<= 1) {
        s.x += __shfl_xor(s.x, off);
        s.y += __shfl_xor(s.y, off);
        s.z += __shfl_xor(s.z, off);
        s.w += __shfl_xor(s.w, off);
    }
    return s;
}

__global__ __launch_bounds__(1024) void k_out(
    const int* __restrict__ cnt, const uint16_t* __restrict__ row,
    const int* __restrict__ govf, const int* __restrict__ ovfcnt,
    const float* __restrict__ h,
    const float* __restrict__ W2l, const float* __restrict__ b2l,
    const float* __restrict__ W2r,
    float* __restrict__ out)
{
    __shared__ float sW[HIDDEN][2][OUT_CH];   // 8 KiB
    __shared__ float sm[16][HIDDEN];
    __shared__ float sh[16][HIDDEN];
    const int t = threadIdx.x;

    const int lane = t & 63;
    const int wid  = t >> 6;
    const int n = blockIdx.x * 16 + wid;      // 3125 * 16 = exactly 50000
    const int q  = lane & 3;
    const int ri = lane >> 2;

    const int dgr   = cnt[n];
    const int slots = dgr < ROWCAP ? dgr : ROWCAP;
    const uint16_t* rp = row + (size_t)n * ROWCAP;

    float4 s = gather_rows_f4(h, rp, slots, ri, q);

    if (dgr > ROWCAP) {
        const int b = n >> 6;
        const int on = ovfcnt[b];
        for (int o = 0; o < on; ++o) {
            const int w = govf[b * OVFCAP + o];
            if (((w >> 16) & 63) == (n & 63)) {
                const float4 v = ((const float4*)(h + (w & 0xFFFF) * HIDDEN))[q];
                s.x += v.x; s.y += v.y; s.z += v.z; s.w += v.w;
            }
        }
    }

    if (lane < 4) {
        const float inv = 1.0f / fmaxf((float)dgr, 1.0f);
        float4 m4;
        m4.x = s.x * inv; m4.y = s.y * inv; m4.z = s.z * inv; m4.w = s.w * inv;
        ((float4*)&sm[wid][0])[q] = m4;
        ((float4*)&sh[wid][0])[q] = ((const float4*)(h + (size_t)n * HIDDEN))[q];
    }

    {
        const int k = t / OUT_CH, c2 = t % OUT_CH;
        sW[k][0][c2] = W2l[t];
        sW[k][1][c2] = W2r[t];
    }
    __syncthreads();

    float acc = b2l[lane];
    #pragma unroll
    for (int k = 0; k < HIDDEN; ++k)
        acc += sm[wid][k] * sW[k][0][lane] + sh[wid][k] * sW[k][1][lane];

    float mx = acc;
    #pragma unroll
    for (int off = 32; off > 0; off >>= 1)
        mx = fmaxf(mx, __shfl_xor(mx, off));
    float ex = expf(acc - mx);
    float sum = ex;
    #pragma unroll
    for (int off = 32; off > 0; off >>= 1)
        sum += __shfl_xor(sum, off);

    out[(size_t)n * OUT_CH + lane] = acc - mx - logf(sum);
}

// ---------------------------------------------------------------------------
extern "C" void kernel_launch(void* const* d_in, const int* in_sizes, int n_in,
                              void* d_out, int out_size, void* d_ws, size_t ws_size,
                              hipStream_t stream)
{
    const float* x   = (const float*)d_in[0];
    const float* W1l = (const float*)d_in[1];
    const float* b1l = (const float*)d_in[2];
    const float* W1r = (const float*)d_in[3];
    const float* W2l = (const float*)d_in[4];
    const float* b2l = (const float*)d_in[5];
    const float* W2r = (const float*)d_in[6];
    const int*   ei  = (const int*)d_in[7];
    float* out = (float*)d_out;

    const size_t NH = (size_t)N_NODES * HIDDEN;           // 800000
    int*   bucket = (int*)d_ws;                           // [PB*PEB]    3.2 MB
    float* bufA   = (float*)(bucket + (size_t)PB * PEB);  // y1          3.2 MB
    float* bufB   = bufA + NH;                            // z1 -> h     3.2 MB
    int*   cnt    = (int*)(bufB + NH);                    // [NPAD]      0.2 MB
    int*   govf   = cnt + NPAD;                           // [NBB*64]    0.2 MB
    int*   ovfcnt = govf + NBB * OVFCAP;                  // [NBB] (+2 pad)
    uint16_t* base16 = (uint16_t*)(ovfcnt + NBB + 2);     // [PB*784]    0.31 MB
    uint16_t* row    = base16 + (size_t)PB * 784;         // [NPAD*48]   4.8 MB

    // K1: partition (blocks 0..PB-1) || linear1 (blocks PB..PB+LB-1)
    k_front<<<PB + LB, 256, 0, stream>>>(ei, bucket, base16,
                                         x, W1l, W1r, bufA, bufB);

    // K2: bin + gather_h fused per bucket (row stays in LDS for the gather)
    k_bin_h<<<NBB, 256, 0, stream>>>(bucket, base16, row, cnt, govf, ovfcnt,
                                     bufA, bufB, b1l);

    // K3: fused gather2 + linear2 + log_softmax
    k_out<<<N_NODES / 16, 1024, 0, stream>>>(cnt, row, govf, ovfcnt, bufB,
                                             W2l, b2l, W2r, out);
}